// Round 2
// baseline (2804.292 us; speedup 1.0000x reference)
//
#include <hip/hip_runtime.h>
#include <math.h>

#pragma clang fp contract(off)

constexpr int NB  = 16;    // batch
constexpr int NR  = 4096;  // rois per image
constexpr int NC  = 81;    // classes (incl. background)
constexpr int KK  = 200;   // per-class candidate cap == max_total
constexpr int CAP = 4096;  // max candidates per image (<= NR, each roi -> <=1 class)
constexpr float SCORE_TH = 0.5f;
constexpr float IOU_TH   = 0.5f;
constexpr float EPSF     = 1e-8f;

struct Entry {            // 32 bytes
    float s;              // score
    int   cls;            // class index
    int   aux;            // roi index (cand list) or pre-NMS rank k (final list)
    int   pad;
    float y1, x1, y2, x2; // un-clipped decoded box
};
static_assert(sizeof(Entry) == 32, "Entry must be 32B");

__global__ void k_init(int* counts) {
    int i = threadIdx.x;
    if (i < 2 * NB) counts[i] = 0;
}

// One thread per ROI: argmax over 81 probs; candidates decoded + appended.
__global__ void k_classify(const float* __restrict__ roi,
                           const float* __restrict__ deltas,
                           const float* __restrict__ probs,
                           int* __restrict__ cand_count,
                           Entry* __restrict__ cand) {
    int r = blockIdx.x * blockDim.x + threadIdx.x;
    if (r >= NB * NR) return;
    int b = r / NR;
    const float* p = probs + (size_t)r * NC;
    float m = p[0];
    int am = 0;
    for (int c = 1; c < NC; ++c) {
        float v = p[c];
        if (v > m) { m = v; am = c; }   // first-max == jnp.argmax tie rule
    }
    if (am == 0 || !(m > SCORE_TH)) return;  // bg or below threshold

    // decode box exactly per reference (delta * variance, delta_to_bbox)
    const float* a = roi + (size_t)r * 4;
    const float* d = deltas + ((size_t)r * NC + am) * 4;
    float ah  = a[2] - a[0];
    float aw  = a[3] - a[1];
    float acy = a[0] + 0.5f * ah;
    float acx = a[1] + 0.5f * aw;
    float dy = d[0] * 0.1f, dx = d[1] * 0.1f;
    float dh = d[2] * 0.2f, dw = d[3] * 0.2f;
    float bh  = expf(dh) * ah;
    float bw  = expf(dw) * aw;
    float bcy = dy * ah + acy;
    float bcx = dx * aw + acx;
    float y1 = bcy - 0.5f * bh;
    float x1 = bcx - 0.5f * bw;
    float y2 = y1 + bh;
    float x2 = x1 + bw;

    int slot = atomicAdd(&cand_count[b], 1);
    if (slot < CAP) {
        Entry* e = &cand[(size_t)b * CAP + slot];
        e->s = m; e->cls = am; e->aux = r % NR; e->pad = 0;
        e->y1 = y1; e->x1 = x1; e->y2 = y2; e->x2 = x2;
    }
}

// One block per (image, class): stable rank -> top-200 -> greedy NMS -> append kept.
__global__ void k_perclass(const int* __restrict__ cand_count,
                           const Entry* __restrict__ cand,
                           int* __restrict__ final_count,
                           Entry* __restrict__ fin) {
    int b = blockIdx.x / NC;
    int c = blockIdx.x % NC;
    if (c == 0) return;  // background class can never have score > 0.5
    int M = cand_count[b];
    if (M > CAP) M = CAP;
    const Entry* list = cand + (size_t)b * CAP;

    __shared__ float ss[KK], sy1[KK], sx1[KK], sy2[KK], sx2[KK], sar[KK];
    __shared__ int   skeep[KK];
    __shared__ int   sMc;
    if (threadIdx.x == 0) sMc = 0;
    __syncthreads();

    // rank candidates of class c by (score desc, roi asc) — lax.top_k stable order
    for (int e = threadIdx.x; e < M; e += blockDim.x) {
        Entry en = list[e];
        if (en.cls != c) continue;
        atomicAdd(&sMc, 1);
        int rank = 0;
        for (int j = 0; j < M; ++j) {
            float sj = list[j].s;
            int   cj = list[j].cls;
            int   rj = list[j].aux;
            if (cj == c && (sj > en.s || (sj == en.s && rj < en.aux))) rank++;
        }
        if (rank < KK) {
            ss[rank] = en.s;
            sy1[rank] = en.y1; sx1[rank] = en.x1;
            sy2[rank] = en.y2; sx2[rank] = en.x2;
            sar[rank] = fmaxf(en.y2 - en.y1, 0.f) * fmaxf(en.x2 - en.x1, 0.f);
        }
    }
    __syncthreads();

    int L = sMc < KK ? sMc : KK;
    if (L == 0) return;

    for (int i = threadIdx.x; i < L; i += blockDim.x) skeep[i] = 1;
    __syncthreads();

    // greedy NMS, sequential over i, parallel over j (reference scan semantics)
    for (int i = 0; i < L; ++i) {
        if (skeep[i]) {              // uniform branch (shared value)
            float yi1 = sy1[i], xi1 = sx1[i], yi2 = sy2[i], xi2 = sx2[i], ai = sar[i];
            for (int j = i + 1 + threadIdx.x; j < L; j += blockDim.x) {
                if (!skeep[j]) continue;
                float yy1 = fmaxf(yi1, sy1[j]), xx1 = fmaxf(xi1, sx1[j]);
                float yy2 = fminf(yi2, sy2[j]), xx2 = fminf(xi2, sx2[j]);
                float inter = fmaxf(yy2 - yy1, 0.f) * fmaxf(xx2 - xx1, 0.f);
                float uni = ai + sar[j] - inter;
                if (inter / (uni + EPSF) > IOU_TH) skeep[j] = 0;
            }
        }
        __syncthreads();
    }

    // append kept entries with their pre-NMS rank (tie key for image-level top-k)
    for (int i = threadIdx.x; i < L; i += blockDim.x) {
        if (skeep[i]) {
            int slot = atomicAdd(&final_count[b], 1);
            if (slot < CAP) {
                Entry* fo = &fin[(size_t)b * CAP + slot];
                fo->s = ss[i]; fo->cls = c; fo->aux = i; fo->pad = 0;
                fo->y1 = sy1[i]; fo->x1 = sx1[i]; fo->y2 = sy2[i]; fo->x2 = sx2[i];
            }
        }
    }
}

// One block per image: stable top-200 by (score desc, c*K+k asc), write outputs.
__global__ void k_topk(const int* __restrict__ final_count,
                       const Entry* __restrict__ fin,
                       float* __restrict__ out) {
    int b = blockIdx.x;
    int M = final_count[b];
    if (M > CAP) M = CAP;
    float* obox = out + (size_t)b * KK * 4;
    float* olbl = out + (size_t)NB * KK * 4 + (size_t)b * KK;
    float* osc  = out + (size_t)NB * KK * 5 + (size_t)b * KK;

    for (int i = threadIdx.x; i < KK; i += blockDim.x) {
        obox[i * 4 + 0] = 0.f; obox[i * 4 + 1] = 0.f;
        obox[i * 4 + 2] = 0.f; obox[i * 4 + 3] = 0.f;
        olbl[i] = 0.f; osc[i] = 0.f;
    }
    __syncthreads();

    const Entry* list = fin + (size_t)b * CAP;
    for (int e = threadIdx.x; e < M; e += blockDim.x) {
        Entry en = list[e];
        int key = en.cls * KK + en.aux;
        int rank = 0;
        for (int j = 0; j < M; ++j) {
            float sj = list[j].s;
            int   kj = list[j].cls * KK + list[j].aux;
            if (sj > en.s || (sj == en.s && kj < key)) rank++;
        }
        if (rank < KK) {
            obox[rank * 4 + 0] = fminf(fmaxf(en.y1, 0.f), 1.f);
            obox[rank * 4 + 1] = fminf(fmaxf(en.x1, 0.f), 1.f);
            obox[rank * 4 + 2] = fminf(fmaxf(en.y2, 0.f), 1.f);
            obox[rank * 4 + 3] = fminf(fmaxf(en.x2, 0.f), 1.f);
            olbl[rank] = (float)en.cls;
            osc[rank]  = en.s;
        }
    }
}

extern "C" void kernel_launch(void* const* d_in, const int* in_sizes, int n_in,
                              void* d_out, int out_size, void* d_ws, size_t ws_size,
                              hipStream_t stream) {
    const float* roi    = (const float*)d_in[0];
    const float* deltas = (const float*)d_in[1];
    const float* probs  = (const float*)d_in[2];
    float* out = (float*)d_out;

    int*   counts      = (int*)d_ws;             // cand_count[16] | final_count[16]
    int*   cand_count  = counts;
    int*   final_count = counts + NB;
    Entry* cand = (Entry*)((char*)d_ws + 256);
    Entry* fin  = cand + (size_t)NB * CAP;       // +2 MB

    k_init<<<1, 64, 0, stream>>>(counts);
    k_classify<<<(NB * NR) / 256, 256, 0, stream>>>(roi, deltas, probs, cand_count, cand);
    k_perclass<<<NB * NC, 256, 0, stream>>>(cand_count, cand, final_count, fin);
    k_topk<<<NB, 256, 0, stream>>>(final_count, fin, out);
}

// Round 3
// 266.489 us; speedup vs baseline: 10.5231x; 10.5231x over previous
//
#include <hip/hip_runtime.h>
#include <math.h>

#pragma clang fp contract(off)

constexpr int NB  = 16;    // batch
constexpr int NR  = 4096;  // rois per image
constexpr int NC  = 81;    // classes (incl. background)
constexpr int KK  = 200;   // per-class candidate cap == max_total
constexpr int CAP = 4096;  // max candidates per image
constexpr int MAXL = 1024; // LDS-resident segment cap in k_perclass
constexpr float SCORE_TH = 0.5f;
constexpr float IOU_TH   = 0.5f;
constexpr float EPSF     = 1e-8f;

struct Entry {            // 32 bytes
    float s;
    int   cls;
    int   aux;            // roi index (cand) or pre-NMS rank k (final)
    int   pad;
    float y1, x1, y2, x2;
};
static_assert(sizeof(Entry) == 32, "Entry must be 32B");

struct SC { float s; int cls; };  // 8B packed per-roi result

// zero counts[NB*NC] and final_count[NB]
__global__ void k_init(int* __restrict__ counts, int* __restrict__ final_count) {
    int i = blockIdx.x * blockDim.x + threadIdx.x;
    if (i < NB * NC) counts[i] = 0;
    if (i < NB) final_count[i] = 0;
}

// One thread per ROI: argmax over 81 probs; store (score,cls); count per (b,c).
__global__ void k_count(const float* __restrict__ probs,
                        SC* __restrict__ sc,
                        int* __restrict__ counts) {
    int r = blockIdx.x * blockDim.x + threadIdx.x;
    if (r >= NB * NR) return;
    const float* p = probs + (size_t)r * NC;
    float m = p[0];
    int am = 0;
    for (int c = 1; c < NC; ++c) {
        float v = p[c];
        if (v > m) { m = v; am = c; }   // first-max == jnp.argmax tie rule
    }
    int cls = (am != 0 && m > SCORE_TH) ? am : 0;  // bg or below threshold -> 0
    sc[r].s = m; sc[r].cls = cls;
    if (cls) atomicAdd(&counts[(r / NR) * NC + cls], 1);
}

// Per image: exclusive prefix sum over class counts; zero cursors.
__global__ void k_offsets(const int* __restrict__ counts,
                          int* __restrict__ offsets,
                          int* __restrict__ cursor) {
    int b = blockIdx.x;
    if (threadIdx.x == 0) {
        int run = 0;
        for (int c = 0; c < NC; ++c) {
            offsets[b * NC + c] = run;
            run += counts[b * NC + c];
            cursor[b * NC + c] = 0;
        }
    }
}

// One thread per ROI: decode candidate box, scatter into its (b,c) segment.
__global__ void k_scatter(const float* __restrict__ roi,
                          const float* __restrict__ deltas,
                          const SC* __restrict__ sc,
                          const int* __restrict__ offsets,
                          int* __restrict__ cursor,
                          Entry* __restrict__ cand) {
    int r = blockIdx.x * blockDim.x + threadIdx.x;
    if (r >= NB * NR) return;
    int cls = sc[r].cls;
    if (cls == 0) return;
    int b = r / NR;
    float m = sc[r].s;

    const float* a = roi + (size_t)r * 4;
    const float* d = deltas + ((size_t)r * NC + cls) * 4;
    float ah  = a[2] - a[0];
    float aw  = a[3] - a[1];
    float acy = a[0] + 0.5f * ah;
    float acx = a[1] + 0.5f * aw;
    float dy = d[0] * 0.1f, dx = d[1] * 0.1f;
    float dh = d[2] * 0.2f, dw = d[3] * 0.2f;
    float bh  = expf(dh) * ah;
    float bw  = expf(dw) * aw;
    float bcy = dy * ah + acy;
    float bcx = dx * aw + acx;
    float y1 = bcy - 0.5f * bh;
    float x1 = bcx - 0.5f * bw;
    float y2 = y1 + bh;
    float x2 = x1 + bw;

    int k = atomicAdd(&cursor[b * NC + cls], 1);
    Entry* e = &cand[(size_t)b * CAP + offsets[b * NC + cls] + k];
    e->s = m; e->cls = cls; e->aux = r % NR; e->pad = 0;
    e->y1 = y1; e->x1 = x1; e->y2 = y2; e->x2 = x2;
}

// One block per (image,class): LDS rank -> top-200 -> greedy NMS -> append kept.
__global__ void k_perclass(const int* __restrict__ counts,
                           const int* __restrict__ offsets,
                           const Entry* __restrict__ cand,
                           int* __restrict__ final_count,
                           Entry* __restrict__ fin) {
    int b = blockIdx.x / NC;
    int c = blockIdx.x % NC;
    if (c == 0) return;
    int Mc = counts[b * NC + c];
    if (Mc == 0) return;
    const Entry* seg = cand + (size_t)b * CAP + offsets[b * NC + c];

    __shared__ float ls[MAXL], ly1[MAXL], lx1[MAXL], ly2[MAXL], lx2[MAXL];
    __shared__ int   lroi[MAXL];
    __shared__ float ss[KK], sy1[KK], sx1[KK], sy2[KK], sx2[KK], sar[KK];
    __shared__ int   skeep[KK];

    bool use_lds = (Mc <= MAXL);
    if (use_lds) {
        for (int i = threadIdx.x; i < Mc; i += blockDim.x) {
            Entry e = seg[i];
            ls[i] = e.s; lroi[i] = e.aux;
            ly1[i] = e.y1; lx1[i] = e.x1; ly2[i] = e.y2; lx2[i] = e.x2;
        }
        __syncthreads();
    }

    // stable rank by (score desc, roi asc) — lax.top_k order
    for (int i = threadIdx.x; i < Mc; i += blockDim.x) {
        float si; int ri; float y1, x1, y2, x2;
        if (use_lds) { si = ls[i]; ri = lroi[i]; y1 = ly1[i]; x1 = lx1[i]; y2 = ly2[i]; x2 = lx2[i]; }
        else { Entry e = seg[i]; si = e.s; ri = e.aux; y1 = e.y1; x1 = e.x1; y2 = e.y2; x2 = e.x2; }
        int rank = 0;
        if (use_lds) {
            for (int j = 0; j < Mc; ++j) {
                float sj = ls[j]; int rj = lroi[j];
                rank += (int)((sj > si) | ((sj == si) & (rj < ri)));
            }
        } else {
            for (int j = 0; j < Mc; ++j) {
                float sj = seg[j].s; int rj = seg[j].aux;
                rank += (int)((sj > si) | ((sj == si) & (rj < ri)));
            }
        }
        if (rank < KK) {
            ss[rank] = si;
            sy1[rank] = y1; sx1[rank] = x1; sy2[rank] = y2; sx2[rank] = x2;
            sar[rank] = fmaxf(y2 - y1, 0.f) * fmaxf(x2 - x1, 0.f);
        }
    }
    __syncthreads();

    int L = Mc < KK ? Mc : KK;
    for (int i = threadIdx.x; i < L; i += blockDim.x) skeep[i] = 1;
    __syncthreads();

    // greedy NMS: sequential over i, parallel over j (reference scan semantics)
    for (int i = 0; i < L; ++i) {
        if (skeep[i]) {
            float yi1 = sy1[i], xi1 = sx1[i], yi2 = sy2[i], xi2 = sx2[i], ai = sar[i];
            for (int j = i + 1 + threadIdx.x; j < L; j += blockDim.x) {
                if (!skeep[j]) continue;
                float yy1 = fmaxf(yi1, sy1[j]), xx1 = fmaxf(xi1, sx1[j]);
                float yy2 = fminf(yi2, sy2[j]), xx2 = fminf(xi2, sx2[j]);
                float inter = fmaxf(yy2 - yy1, 0.f) * fmaxf(xx2 - xx1, 0.f);
                float uni = ai + sar[j] - inter;
                if (inter / (uni + EPSF) > IOU_TH) skeep[j] = 0;
            }
        }
        __syncthreads();
    }

    for (int i = threadIdx.x; i < L; i += blockDim.x) {
        if (skeep[i]) {
            int slot = atomicAdd(&final_count[b], 1);
            if (slot < CAP) {
                Entry* fo = &fin[(size_t)b * CAP + slot];
                fo->s = ss[i]; fo->cls = c; fo->aux = i; fo->pad = 0;
                fo->y1 = sy1[i]; fo->x1 = sx1[i]; fo->y2 = sy2[i]; fo->x2 = sx2[i];
            }
        }
    }
}

// One block per image: LDS rank over kept entries by (score desc, c*K+k asc).
__global__ void k_topk(const int* __restrict__ final_count,
                       const Entry* __restrict__ fin,
                       float* __restrict__ out) {
    int b = blockIdx.x;
    int M = final_count[b];
    if (M > CAP) M = CAP;
    float* obox = out + (size_t)b * KK * 4;
    float* olbl = out + (size_t)NB * KK * 4 + (size_t)b * KK;
    float* osc  = out + (size_t)NB * KK * 5 + (size_t)b * KK;

    __shared__ float sS[CAP];
    __shared__ int   sK[CAP];

    const Entry* list = fin + (size_t)b * CAP;
    for (int i = threadIdx.x; i < M; i += blockDim.x) {
        sS[i] = list[i].s;
        sK[i] = list[i].cls * KK + list[i].aux;
    }
    for (int i = threadIdx.x; i < KK; i += blockDim.x) {
        obox[i * 4 + 0] = 0.f; obox[i * 4 + 1] = 0.f;
        obox[i * 4 + 2] = 0.f; obox[i * 4 + 3] = 0.f;
        olbl[i] = 0.f; osc[i] = 0.f;
    }
    __syncthreads();

    for (int e = threadIdx.x; e < M; e += blockDim.x) {
        float se = sS[e]; int ke = sK[e];
        int rank = 0;
        for (int j = 0; j < M; ++j) {
            float sj = sS[j]; int kj = sK[j];
            rank += (int)((sj > se) | ((sj == se) & (kj < ke)));
        }
        if (rank < KK) {
            Entry en = list[e];
            obox[rank * 4 + 0] = fminf(fmaxf(en.y1, 0.f), 1.f);
            obox[rank * 4 + 1] = fminf(fmaxf(en.x1, 0.f), 1.f);
            obox[rank * 4 + 2] = fminf(fmaxf(en.y2, 0.f), 1.f);
            obox[rank * 4 + 3] = fminf(fmaxf(en.x2, 0.f), 1.f);
            olbl[rank] = (float)en.cls;
            osc[rank]  = en.s;
        }
    }
}

extern "C" void kernel_launch(void* const* d_in, const int* in_sizes, int n_in,
                              void* d_out, int out_size, void* d_ws, size_t ws_size,
                              hipStream_t stream) {
    const float* roi    = (const float*)d_in[0];
    const float* deltas = (const float*)d_in[1];
    const float* probs  = (const float*)d_in[2];
    float* out = (float*)d_out;

    int* ws_i        = (int*)d_ws;
    int* counts      = ws_i;                 // NB*NC
    int* offsets     = ws_i + NB * NC;       // NB*NC
    int* cursor      = ws_i + 2 * NB * NC;   // NB*NC
    int* final_count = ws_i + 3 * NB * NC;   // NB
    SC*    sc   = (SC*)((char*)d_ws + 16384);                 // NB*NR * 8B = 512KB
    Entry* cand = (Entry*)((char*)d_ws + 16384 + 524288);     // NB*CAP * 32B = 2MB
    Entry* fin  = cand + (size_t)NB * CAP;                    // +2MB

    k_init<<<(NB * NC + 255) / 256, 256, 0, stream>>>(counts, final_count);
    k_count<<<(NB * NR) / 256, 256, 0, stream>>>(probs, sc, counts);
    k_offsets<<<NB, 64, 0, stream>>>(counts, offsets, cursor);
    k_scatter<<<(NB * NR) / 256, 256, 0, stream>>>(roi, deltas, sc, offsets, cursor, cand);
    k_perclass<<<NB * NC, 256, 0, stream>>>(counts, offsets, cand, final_count, fin);
    k_topk<<<NB, 256, 0, stream>>>(final_count, fin, out);
}

// Round 4
// 86.768 us; speedup vs baseline: 32.3193x; 3.0713x over previous
//
#include <hip/hip_runtime.h>
#include <math.h>

#pragma clang fp contract(off)

constexpr int NB  = 16;    // batch
constexpr int NR  = 4096;  // rois per image
constexpr int NC  = 81;    // classes (incl. background)
constexpr int KK  = 200;   // per-class candidate cap == max_total
constexpr int CAP = 4096;  // max candidates per image
constexpr int MAXL = 1024; // LDS-resident segment cap in k_perclass
constexpr int TCHUNK = 256;               // entries ranked per block in k_topk
constexpr int NCHUNK = CAP / TCHUNK;      // 16 blocks per image
constexpr int OUT_ELEMS = NB * KK * 6;    // boxes(4) + labels(1) + scores(1)
constexpr float SCORE_TH = 0.5f;
constexpr float IOU_TH   = 0.5f;
constexpr float EPSF     = 1e-8f;

struct Entry {            // 32 bytes
    float s;
    int   cls;
    int   aux;            // roi index (cand) or pre-NMS rank k (final)
    int   pad;
    float y1, x1, y2, x2;
};
static_assert(sizeof(Entry) == 32, "Entry must be 32B");

struct SC { float s; int cls; };   // 8B packed per-roi classify result
struct SK { float s; int key; };   // 8B packed (score, cls*KK+prenms_rank)

// zero counts[NB*NC], final_count[NB], and the output buffer
__global__ void k_init(int* __restrict__ counts, int* __restrict__ final_count,
                       float* __restrict__ out) {
    int i = blockIdx.x * blockDim.x + threadIdx.x;
    if (i < NB * NC) counts[i] = 0;
    if (i < NB) final_count[i] = 0;
    for (int j = i; j < OUT_ELEMS; j += gridDim.x * blockDim.x) out[j] = 0.f;
}

// One thread per ROI: argmax over 81 probs; store (score,cls); count per (b,c).
__global__ void k_count(const float* __restrict__ probs,
                        SC* __restrict__ sc,
                        int* __restrict__ counts) {
    int r = blockIdx.x * blockDim.x + threadIdx.x;
    if (r >= NB * NR) return;
    const float* p = probs + (size_t)r * NC;
    float m = p[0];
    int am = 0;
    for (int c = 1; c < NC; ++c) {
        float v = p[c];
        if (v > m) { m = v; am = c; }   // first-max == jnp.argmax tie rule
    }
    int cls = (am != 0 && m > SCORE_TH) ? am : 0;  // bg or below threshold -> 0
    sc[r].s = m; sc[r].cls = cls;
    if (cls) atomicAdd(&counts[(r / NR) * NC + cls], 1);
}

// Per image: exclusive prefix sum over class counts; zero cursors.
__global__ void k_offsets(const int* __restrict__ counts,
                          int* __restrict__ offsets,
                          int* __restrict__ cursor) {
    int b = blockIdx.x;
    if (threadIdx.x == 0) {
        int run = 0;
        for (int c = 0; c < NC; ++c) {
            offsets[b * NC + c] = run;
            run += counts[b * NC + c];
            cursor[b * NC + c] = 0;
        }
    }
}

// One thread per ROI: decode candidate box, scatter into its (b,c) segment.
__global__ void k_scatter(const float* __restrict__ roi,
                          const float* __restrict__ deltas,
                          const SC* __restrict__ sc,
                          const int* __restrict__ offsets,
                          int* __restrict__ cursor,
                          Entry* __restrict__ cand) {
    int r = blockIdx.x * blockDim.x + threadIdx.x;
    if (r >= NB * NR) return;
    int cls = sc[r].cls;
    if (cls == 0) return;
    int b = r / NR;
    float m = sc[r].s;

    const float* a = roi + (size_t)r * 4;
    const float* d = deltas + ((size_t)r * NC + cls) * 4;
    float ah  = a[2] - a[0];
    float aw  = a[3] - a[1];
    float acy = a[0] + 0.5f * ah;
    float acx = a[1] + 0.5f * aw;
    float dy = d[0] * 0.1f, dx = d[1] * 0.1f;
    float dh = d[2] * 0.2f, dw = d[3] * 0.2f;
    float bh  = expf(dh) * ah;
    float bw  = expf(dw) * aw;
    float bcy = dy * ah + acy;
    float bcx = dx * aw + acx;
    float y1 = bcy - 0.5f * bh;
    float x1 = bcx - 0.5f * bw;
    float y2 = y1 + bh;
    float x2 = x1 + bw;

    int k = atomicAdd(&cursor[b * NC + cls], 1);
    Entry* e = &cand[(size_t)b * CAP + offsets[b * NC + cls] + k];
    e->s = m; e->cls = cls; e->aux = r % NR; e->pad = 0;
    e->y1 = y1; e->x1 = x1; e->y2 = y2; e->x2 = x2;
}

// One block per (image,class): LDS rank -> top-200 -> greedy NMS -> append kept.
__global__ void k_perclass(const int* __restrict__ counts,
                           const int* __restrict__ offsets,
                           const Entry* __restrict__ cand,
                           int* __restrict__ final_count,
                           Entry* __restrict__ fin,
                           SK* __restrict__ sk) {
    int b = blockIdx.x / NC;
    int c = blockIdx.x % NC;
    if (c == 0) return;
    int Mc = counts[b * NC + c];
    if (Mc == 0) return;
    const Entry* seg = cand + (size_t)b * CAP + offsets[b * NC + c];

    __shared__ float ls[MAXL], ly1[MAXL], lx1[MAXL], ly2[MAXL], lx2[MAXL];
    __shared__ int   lroi[MAXL];
    __shared__ float ss[KK], sy1[KK], sx1[KK], sy2[KK], sx2[KK], sar[KK];
    __shared__ int   skeep[KK];

    bool use_lds = (Mc <= MAXL);
    if (use_lds) {
        for (int i = threadIdx.x; i < Mc; i += blockDim.x) {
            Entry e = seg[i];
            ls[i] = e.s; lroi[i] = e.aux;
            ly1[i] = e.y1; lx1[i] = e.x1; ly2[i] = e.y2; lx2[i] = e.x2;
        }
        __syncthreads();
    }

    // stable rank by (score desc, roi asc) — lax.top_k order
    for (int i = threadIdx.x; i < Mc; i += blockDim.x) {
        float si; int ri; float y1, x1, y2, x2;
        if (use_lds) { si = ls[i]; ri = lroi[i]; y1 = ly1[i]; x1 = lx1[i]; y2 = ly2[i]; x2 = lx2[i]; }
        else { Entry e = seg[i]; si = e.s; ri = e.aux; y1 = e.y1; x1 = e.x1; y2 = e.y2; x2 = e.x2; }
        int rank = 0;
        if (use_lds) {
            for (int j = 0; j < Mc; ++j) {
                float sj = ls[j]; int rj = lroi[j];
                rank += (int)((sj > si) | ((sj == si) & (rj < ri)));
            }
        } else {
            for (int j = 0; j < Mc; ++j) {
                float sj = seg[j].s; int rj = seg[j].aux;
                rank += (int)((sj > si) | ((sj == si) & (rj < ri)));
            }
        }
        if (rank < KK) {
            ss[rank] = si;
            sy1[rank] = y1; sx1[rank] = x1; sy2[rank] = y2; sx2[rank] = x2;
            sar[rank] = fmaxf(y2 - y1, 0.f) * fmaxf(x2 - x1, 0.f);
        }
    }
    __syncthreads();

    int L = Mc < KK ? Mc : KK;
    for (int i = threadIdx.x; i < L; i += blockDim.x) skeep[i] = 1;
    __syncthreads();

    // greedy NMS: sequential over i, parallel over j (reference scan semantics)
    for (int i = 0; i < L; ++i) {
        if (skeep[i]) {
            float yi1 = sy1[i], xi1 = sx1[i], yi2 = sy2[i], xi2 = sx2[i], ai = sar[i];
            for (int j = i + 1 + threadIdx.x; j < L; j += blockDim.x) {
                if (!skeep[j]) continue;
                float yy1 = fmaxf(yi1, sy1[j]), xx1 = fmaxf(xi1, sx1[j]);
                float yy2 = fminf(yi2, sy2[j]), xx2 = fminf(xi2, sx2[j]);
                float inter = fmaxf(yy2 - yy1, 0.f) * fmaxf(xx2 - xx1, 0.f);
                float uni = ai + sar[j] - inter;
                if (inter / (uni + EPSF) > IOU_TH) skeep[j] = 0;
            }
        }
        __syncthreads();
    }

    for (int i = threadIdx.x; i < L; i += blockDim.x) {
        if (skeep[i]) {
            int slot = atomicAdd(&final_count[b], 1);
            if (slot < CAP) {
                Entry* fo = &fin[(size_t)b * CAP + slot];
                fo->s = ss[i]; fo->cls = c; fo->aux = i; fo->pad = 0;
                fo->y1 = sy1[i]; fo->x1 = sx1[i]; fo->y2 = sy2[i]; fo->x2 = sx2[i];
                sk[(size_t)b * CAP + slot].s = ss[i];
                sk[(size_t)b * CAP + slot].key = c * KK + i;
            }
        }
    }
}

// NCHUNK blocks per image: each thread ranks ONE entry against the full list
// (resident in LDS), writes its output row directly (ranks unique -> no race).
// Output buffer was pre-zeroed by k_init.
__global__ void k_topk(const int* __restrict__ final_count,
                       const Entry* __restrict__ fin,
                       const SK* __restrict__ sk,
                       float* __restrict__ out) {
    int b     = blockIdx.x / NCHUNK;
    int chunk = blockIdx.x % NCHUNK;
    int M = final_count[b];
    if (M > CAP) M = CAP;
    if (chunk * TCHUNK >= M) return;

    __shared__ float sS[CAP];
    __shared__ int   sKy[CAP];
    const SK* list = sk + (size_t)b * CAP;
    for (int i = threadIdx.x; i < M; i += blockDim.x) {
        SK v = list[i];
        sS[i] = v.s; sKy[i] = v.key;
    }
    __syncthreads();

    int e = chunk * TCHUNK + threadIdx.x;
    if (e >= M) return;
    float se = sS[e]; int ke = sKy[e];
    int rank = 0;
    for (int j = 0; j < M; ++j) {
        float sj = sS[j]; int kj = sKy[j];
        rank += (int)((sj > se) | ((sj == se) & (kj < ke)));
    }
    if (rank < KK) {
        Entry en = fin[(size_t)b * CAP + e];
        float* obox = out + (size_t)b * KK * 4;
        float* olbl = out + (size_t)NB * KK * 4 + (size_t)b * KK;
        float* osc  = out + (size_t)NB * KK * 5 + (size_t)b * KK;
        obox[rank * 4 + 0] = fminf(fmaxf(en.y1, 0.f), 1.f);
        obox[rank * 4 + 1] = fminf(fmaxf(en.x1, 0.f), 1.f);
        obox[rank * 4 + 2] = fminf(fmaxf(en.y2, 0.f), 1.f);
        obox[rank * 4 + 3] = fminf(fmaxf(en.x2, 0.f), 1.f);
        olbl[rank] = (float)en.cls;
        osc[rank]  = en.s;
    }
}

extern "C" void kernel_launch(void* const* d_in, const int* in_sizes, int n_in,
                              void* d_out, int out_size, void* d_ws, size_t ws_size,
                              hipStream_t stream) {
    const float* roi    = (const float*)d_in[0];
    const float* deltas = (const float*)d_in[1];
    const float* probs  = (const float*)d_in[2];
    float* out = (float*)d_out;

    int* ws_i        = (int*)d_ws;
    int* counts      = ws_i;                 // NB*NC
    int* offsets     = ws_i + NB * NC;       // NB*NC
    int* cursor      = ws_i + 2 * NB * NC;   // NB*NC
    int* final_count = ws_i + 3 * NB * NC;   // NB
    SC*    sc   = (SC*)((char*)d_ws + 16384);                 // 512KB
    Entry* cand = (Entry*)((char*)d_ws + 16384 + 524288);     // 2MB
    Entry* fin  = cand + (size_t)NB * CAP;                    // 2MB
    SK*    sk   = (SK*)(fin + (size_t)NB * CAP);              // 512KB

    k_init<<<80, 256, 0, stream>>>(counts, final_count, out);
    k_count<<<(NB * NR) / 256, 256, 0, stream>>>(probs, sc, counts);
    k_offsets<<<NB, 64, 0, stream>>>(counts, offsets, cursor);
    k_scatter<<<(NB * NR) / 256, 256, 0, stream>>>(roi, deltas, sc, offsets, cursor, cand);
    k_perclass<<<NB * NC, 256, 0, stream>>>(counts, offsets, cand, final_count, fin, sk);
    k_topk<<<NB * NCHUNK, 256, 0, stream>>>(final_count, fin, sk, out);
}

// Round 5
// 84.240 us; speedup vs baseline: 33.2892x; 1.0300x over previous
//
#include <hip/hip_runtime.h>
#include <math.h>

#pragma clang fp contract(off)

constexpr int NB  = 16;    // batch
constexpr int NR  = 4096;  // rois per image
constexpr int NC  = 81;    // classes (incl. background)
constexpr int KK  = 200;   // per-class candidate cap == max_total
constexpr int CAP = 4096;  // max kept entries per image (<= NR)
constexpr int SEGCAP = 1024;  // fixed-stride per-(b,c) candidate segment
constexpr int ROWS_PER_BLK = 64;
constexpr int TCHUNK = 256;               // entries ranked per block in k_topk
constexpr int NCHUNK = CAP / TCHUNK;      // 16 blocks per image
constexpr int OUT_ELEMS = NB * KK * 6;    // boxes(4) + labels(1) + scores(1)
constexpr float SCORE_TH = 0.5f;
constexpr float IOU_TH   = 0.5f;
constexpr float EPSF     = 1e-8f;

struct Entry {            // 32 bytes
    float s;
    int   cls;
    int   aux;            // roi index (cand) or pre-NMS rank k (final)
    int   pad;
    float y1, x1, y2, x2;
};
static_assert(sizeof(Entry) == 32, "Entry must be 32B");

struct SK { float s; int key; };   // 8B packed (score, cls*KK + prenms_rank)

// zero counts[NB*NC], final_count[NB], and the output buffer
__global__ void k_init(int* __restrict__ counts, int* __restrict__ final_count,
                       float* __restrict__ out) {
    int i = blockIdx.x * blockDim.x + threadIdx.x;
    if (i < NB * NC) counts[i] = 0;
    if (i < NB) final_count[i] = 0;
    for (int j = i; j < OUT_ELEMS; j += gridDim.x * blockDim.x) out[j] = 0.f;
}

// 4 threads per ROI: LDS-staged coalesced probs, shfl argmax (first-max rule),
// leader decodes box and scatters into fixed-stride (b,c) segment.
__global__ void k_classify(const float* __restrict__ roi,
                           const float* __restrict__ deltas,
                           const float* __restrict__ probs,
                           int* __restrict__ counts,
                           Entry* __restrict__ cand) {
    __shared__ float lp[ROWS_PER_BLK * NC];   // 64*81*4 = 20736 B

    // stage 64 rows of probs, float4-coalesced (64*81/4 = 1296 float4)
    const float4* src = (const float4*)(probs + (size_t)blockIdx.x * ROWS_PER_BLK * NC);
    float4* dst = (float4*)lp;
    for (int v = threadIdx.x; v < ROWS_PER_BLK * NC / 4; v += blockDim.x)
        dst[v] = src[v];
    __syncthreads();

    int g = threadIdx.x >> 2;       // row within block
    int j = threadIdx.x & 3;        // sub-lane within row group
    const float* row = lp + g * NC;

    float m = -1.0f;
    int am = 127;
    for (int c = j; c < NC; c += 4) {
        float v = row[c];
        if (v > m) { m = v; am = c; }        // first-max within subset
    }
    // combine 4 partials: larger m wins; tie -> smaller index (== jnp.argmax)
    for (int mask = 1; mask <= 2; mask <<= 1) {
        float om = __shfl_xor(m, mask);
        int   oi = __shfl_xor(am, mask);
        if (om > m || (om == m && oi < am)) { m = om; am = oi; }
    }
    if (j != 0) return;
    if (am == 0 || !(m > SCORE_TH)) return;  // background or below threshold

    int r = blockIdx.x * ROWS_PER_BLK + g;
    int b = r / NR;

    float4 a = ((const float4*)roi)[r];                       // y1,x1,y2,x2
    float4 d = *(const float4*)(deltas + ((size_t)r * NC + am) * 4);
    float ah  = a.z - a.x;
    float aw  = a.w - a.y;
    float acy = a.x + 0.5f * ah;
    float acx = a.y + 0.5f * aw;
    float dy = d.x * 0.1f, dx = d.y * 0.1f;
    float dh = d.z * 0.2f, dw = d.w * 0.2f;
    float bh  = expf(dh) * ah;
    float bw  = expf(dw) * aw;
    float bcy = dy * ah + acy;
    float bcx = dx * aw + acx;
    float y1 = bcy - 0.5f * bh;
    float x1 = bcx - 0.5f * bw;
    float y2 = y1 + bh;
    float x2 = x1 + bw;

    int slot = atomicAdd(&counts[b * NC + am], 1);
    if (slot < SEGCAP) {
        Entry* e = &cand[(size_t)(b * NC + am) * SEGCAP + slot];
        e->s = m; e->cls = am; e->aux = r % NR; e->pad = 0;
        e->y1 = y1; e->x1 = x1; e->y2 = y2; e->x2 = x2;
    }
}

// One block per (image,class): LDS rank -> top-200 -> greedy NMS -> append kept
// (single aggregated atomic per block).
__global__ void k_perclass(const int* __restrict__ counts,
                           const Entry* __restrict__ cand,
                           int* __restrict__ final_count,
                           Entry* __restrict__ fin,
                           SK* __restrict__ sk) {
    int b = blockIdx.x / NC;
    int c = blockIdx.x % NC;
    if (c == 0) return;
    int Mc = counts[b * NC + c];
    if (Mc > SEGCAP) Mc = SEGCAP;
    if (Mc == 0) return;
    const Entry* seg = cand + (size_t)(b * NC + c) * SEGCAP;

    __shared__ float ls[SEGCAP], ly1[SEGCAP], lx1[SEGCAP], ly2[SEGCAP], lx2[SEGCAP];
    __shared__ int   lroi[SEGCAP];
    __shared__ float ss[KK], sy1[KK], sx1[KK], sy2[KK], sx2[KK], sar[KK];
    __shared__ int   skeep[KK];
    __shared__ int   sbase;

    for (int i = threadIdx.x; i < Mc; i += blockDim.x) {
        Entry e = seg[i];
        ls[i] = e.s; lroi[i] = e.aux;
        ly1[i] = e.y1; lx1[i] = e.x1; ly2[i] = e.y2; lx2[i] = e.x2;
    }
    __syncthreads();

    // stable rank by (score desc, roi asc) — lax.top_k order
    for (int i = threadIdx.x; i < Mc; i += blockDim.x) {
        float si = ls[i]; int ri = lroi[i];
        int rank = 0;
        for (int j = 0; j < Mc; ++j) {
            float sj = ls[j]; int rj = lroi[j];
            rank += (int)((sj > si) | ((sj == si) & (rj < ri)));
        }
        if (rank < KK) {
            ss[rank] = si;
            sy1[rank] = ly1[i]; sx1[rank] = lx1[i];
            sy2[rank] = ly2[i]; sx2[rank] = lx2[i];
            sar[rank] = fmaxf(ly2[i] - ly1[i], 0.f) * fmaxf(lx2[i] - lx1[i], 0.f);
        }
    }
    __syncthreads();

    int L = Mc < KK ? Mc : KK;
    for (int i = threadIdx.x; i < L; i += blockDim.x) skeep[i] = 1;
    __syncthreads();

    // greedy NMS: sequential over i, parallel over j (reference scan semantics)
    for (int i = 0; i < L; ++i) {
        if (skeep[i]) {
            float yi1 = sy1[i], xi1 = sx1[i], yi2 = sy2[i], xi2 = sx2[i], ai = sar[i];
            for (int j = i + 1 + threadIdx.x; j < L; j += blockDim.x) {
                if (!skeep[j]) continue;
                float yy1 = fmaxf(yi1, sy1[j]), xx1 = fmaxf(xi1, sx1[j]);
                float yy2 = fminf(yi2, sy2[j]), xx2 = fminf(xi2, sx2[j]);
                float inter = fmaxf(yy2 - yy1, 0.f) * fmaxf(xx2 - xx1, 0.f);
                float uni = ai + sar[j] - inter;
                if (inter / (uni + EPSF) > IOU_TH) skeep[j] = 0;
            }
        }
        __syncthreads();
    }

    // one atomic per block, then parallel prefix compaction into [sbase, ...)
    if (threadIdx.x == 0) {
        int tot = 0;
        for (int i = 0; i < L; ++i) tot += skeep[i];
        sbase = atomicAdd(&final_count[b], tot);
    }
    __syncthreads();
    int base = sbase;

    for (int i = threadIdx.x; i < L; i += blockDim.x) {
        if (skeep[i]) {
            int pos = 0;
            for (int j = 0; j < i; ++j) pos += skeep[j];
            int slot = base + pos;
            if (slot < CAP) {
                Entry* fo = &fin[(size_t)b * CAP + slot];
                fo->s = ss[i]; fo->cls = c; fo->aux = i; fo->pad = 0;
                fo->y1 = sy1[i]; fo->x1 = sx1[i]; fo->y2 = sy2[i]; fo->x2 = sx2[i];
                sk[(size_t)b * CAP + slot].s = ss[i];
                sk[(size_t)b * CAP + slot].key = c * KK + i;
            }
        }
    }
}

// NCHUNK blocks per image: each thread ranks ONE entry against the full list
// (LDS-resident), writes its output row directly (ranks unique -> no race).
__global__ void k_topk(const int* __restrict__ final_count,
                       const Entry* __restrict__ fin,
                       const SK* __restrict__ sk,
                       float* __restrict__ out) {
    int b     = blockIdx.x / NCHUNK;
    int chunk = blockIdx.x % NCHUNK;
    int M = final_count[b];
    if (M > CAP) M = CAP;
    if (chunk * TCHUNK >= M) return;

    __shared__ float sS[CAP];
    __shared__ int   sKy[CAP];
    const SK* list = sk + (size_t)b * CAP;
    for (int i = threadIdx.x; i < M; i += blockDim.x) {
        SK v = list[i];
        sS[i] = v.s; sKy[i] = v.key;
    }
    __syncthreads();

    int e = chunk * TCHUNK + threadIdx.x;
    if (e >= M) return;
    float se = sS[e]; int ke = sKy[e];
    int rank = 0;
    for (int j = 0; j < M; ++j) {
        float sj = sS[j]; int kj = sKy[j];
        rank += (int)((sj > se) | ((sj == se) & (kj < ke)));
    }
    if (rank < KK) {
        Entry en = fin[(size_t)b * CAP + e];
        float* obox = out + (size_t)b * KK * 4;
        float* olbl = out + (size_t)NB * KK * 4 + (size_t)b * KK;
        float* osc  = out + (size_t)NB * KK * 5 + (size_t)b * KK;
        obox[rank * 4 + 0] = fminf(fmaxf(en.y1, 0.f), 1.f);
        obox[rank * 4 + 1] = fminf(fmaxf(en.x1, 0.f), 1.f);
        obox[rank * 4 + 2] = fminf(fmaxf(en.y2, 0.f), 1.f);
        obox[rank * 4 + 3] = fminf(fmaxf(en.x2, 0.f), 1.f);
        olbl[rank] = (float)en.cls;
        osc[rank]  = en.s;
    }
}

extern "C" void kernel_launch(void* const* d_in, const int* in_sizes, int n_in,
                              void* d_out, int out_size, void* d_ws, size_t ws_size,
                              hipStream_t stream) {
    const float* roi    = (const float*)d_in[0];
    const float* deltas = (const float*)d_in[1];
    const float* probs  = (const float*)d_in[2];
    float* out = (float*)d_out;

    int* ws_i        = (int*)d_ws;
    int* counts      = ws_i;                 // NB*NC
    int* final_count = ws_i + NB * NC;       // NB
    Entry* cand = (Entry*)((char*)d_ws + 16384);              // NB*NC*SEGCAP*32B = 42.5MB
    Entry* fin  = cand + (size_t)NB * NC * SEGCAP;            // 2MB
    SK*    sk   = (SK*)(fin + (size_t)NB * CAP);              // 512KB

    k_init<<<80, 256, 0, stream>>>(counts, final_count, out);
    k_classify<<<(NB * NR) / ROWS_PER_BLK, 256, 0, stream>>>(roi, deltas, probs, counts, cand);
    k_perclass<<<NB * NC, 256, 0, stream>>>(counts, cand, final_count, fin, sk);
    k_topk<<<NB * NCHUNK, 256, 0, stream>>>(final_count, fin, sk, out);
}